// Round 1
// baseline (1456.172 us; speedup 1.0000x reference)
//
#include <hip/hip_runtime.h>

// LSTMTrafficPredictor: fused 2-layer LSTM + FC head, fp32.
// B=2048, T=512, IN=4, H1=64, H2=32, FC=16, OUT=1.
// One block = NB=4 batch elements; whole T-loop inside the kernel.
// Weights in registers (thread t: Whh1 row t, layer2 gate row t%128);
// h/c state + gate exchange via LDS (same-address broadcast reads).

#define T_LEN 512
#define IN_F  4
#define H1    64
#define H2    32
#define FCN   16
#define NB    4
#define BLK   256

__device__ __forceinline__ float sigm(float x) {
    return 1.0f / (1.0f + __expf(-x));
}
__device__ __forceinline__ float tanh_(float x) {
    // 1 - 2/(e^{2x}+1): saturates correctly for large |x| (inf-safe)
    return 1.0f - 2.0f / (__expf(2.0f * x) + 1.0f);
}

__global__ __launch_bounds__(BLK, 2)
void lstm_fused(const float* __restrict__ x,
                const float* __restrict__ Wih1, const float* __restrict__ Whh1,
                const float* __restrict__ bih1, const float* __restrict__ bhh1,
                const float* __restrict__ Wih2, const float* __restrict__ Whh2,
                const float* __restrict__ bih2, const float* __restrict__ bhh2,
                const float* __restrict__ fc1_w, const float* __restrict__ fc1_b,
                const float* __restrict__ fc2_w, const float* __restrict__ fc2_b,
                float* __restrict__ out)
{
    __shared__ __align__(16) float x_s[NB][T_LEN * IN_F];   // 32 KB
    __shared__ __align__(16) float h1_s[NB][H1];            // 1 KB
    __shared__ __align__(16) float h2_s[NB][H2];            // 0.5 KB
    __shared__ __align__(16) float g1_s[NB][4 * H1];        // 4 KB
    __shared__ __align__(16) float g2_s[NB][4 * H2];        // 2 KB

    const int t  = threadIdx.x;
    const int b0 = blockIdx.x * NB;

    // ---- stage x for our NB batches (contiguous, coalesced float4) ----
    {
        const float4* src = (const float4*)(x + (size_t)b0 * T_LEN * IN_F);
        float4* dst = (float4*)&x_s[0][0];
        #pragma unroll
        for (int i = 0; i < (NB * T_LEN * IN_F / 4) / BLK; ++i)
            dst[t + i * BLK] = src[t + i * BLK];
    }

    // ---- load per-thread weight rows into registers ----
    float wih1[IN_F], whh1[H1];
    const float b1 = bih1[t] + bhh1[t];
    #pragma unroll
    for (int i = 0; i < IN_F; ++i) wih1[i] = Wih1[t * IN_F + i];
    #pragma unroll
    for (int j = 0; j < H1; ++j) whh1[j] = Whh1[t * H1 + j];

    const int g2i = t & (4 * H2 - 1);   // layer2 gate row 0..127
    const int bp  = t >> 7;             // batch pair 0..1
    float wih2[H1], whh2[H2];
    const float b2 = bih2[g2i] + bhh2[g2i];
    #pragma unroll
    for (int j = 0; j < H1; ++j) wih2[j] = Wih2[g2i * H1 + j];
    #pragma unroll
    for (int j = 0; j < H2; ++j) whh2[j] = Whh2[g2i * H2 + j];

    // ---- init state ----
    float c1 = 0.f;   // unit t&63 of batch t>>6
    float c2 = 0.f;   // (t<128) unit t&31 of batch t>>5
    for (int i = t; i < NB * H1; i += BLK) (&h1_s[0][0])[i] = 0.f;
    for (int i = t; i < NB * H2; i += BLK) (&h2_s[0][0])[i] = 0.f;
    __syncthreads();

    // ================= main recurrence =================
    for (int step = 0; step < T_LEN; ++step) {
        // ---- layer1 gate pre-activations: thread t = gate t, all NB batches ----
        float acc[NB];
        #pragma unroll
        for (int b = 0; b < NB; ++b) {
            const float4 xv = *((const float4*)&x_s[b][step * IN_F]);
            float a = fmaf(wih1[3], xv.w, b1);
            a = fmaf(wih1[2], xv.z, a);
            a = fmaf(wih1[1], xv.y, a);
            a = fmaf(wih1[0], xv.x, a);
            acc[b] = a;
        }
        #pragma unroll
        for (int j4 = 0; j4 < H1 / 4; ++j4) {
            #pragma unroll
            for (int b = 0; b < NB; ++b) {
                const float4 hv = *((const float4*)&h1_s[b][j4 * 4]);
                acc[b] = fmaf(whh1[4 * j4 + 0], hv.x, acc[b]);
                acc[b] = fmaf(whh1[4 * j4 + 1], hv.y, acc[b]);
                acc[b] = fmaf(whh1[4 * j4 + 2], hv.z, acc[b]);
                acc[b] = fmaf(whh1[4 * j4 + 3], hv.w, acc[b]);
            }
        }
        #pragma unroll
        for (int b = 0; b < NB; ++b) g1_s[b][t] = acc[b];
        __syncthreads();

        // ---- layer1 state update: thread t -> unit t&63, batch t>>6 ----
        {
            const int u = t & (H1 - 1), b = t >> 6;
            const float gi = sigm(g1_s[b][u]);
            const float gf = sigm(g1_s[b][H1 + u]);
            const float gg = tanh_(g1_s[b][2 * H1 + u]);
            const float go = sigm(g1_s[b][3 * H1 + u]);
            c1 = fmaf(gf, c1, gi * gg);
            h1_s[b][u] = go * tanh_(c1);
        }
        __syncthreads();

        // ---- layer2 gate pre-activations: thread t = gate t&127, batches {2bp, 2bp+1} ----
        float acc2[2] = {b2, b2};
        #pragma unroll
        for (int j4 = 0; j4 < H1 / 4; ++j4) {
            #pragma unroll
            for (int k = 0; k < 2; ++k) {
                const float4 hv = *((const float4*)&h1_s[bp * 2 + k][j4 * 4]);
                acc2[k] = fmaf(wih2[4 * j4 + 0], hv.x, acc2[k]);
                acc2[k] = fmaf(wih2[4 * j4 + 1], hv.y, acc2[k]);
                acc2[k] = fmaf(wih2[4 * j4 + 2], hv.z, acc2[k]);
                acc2[k] = fmaf(wih2[4 * j4 + 3], hv.w, acc2[k]);
            }
        }
        #pragma unroll
        for (int j4 = 0; j4 < H2 / 4; ++j4) {
            #pragma unroll
            for (int k = 0; k < 2; ++k) {
                const float4 hv = *((const float4*)&h2_s[bp * 2 + k][j4 * 4]);
                acc2[k] = fmaf(whh2[4 * j4 + 0], hv.x, acc2[k]);
                acc2[k] = fmaf(whh2[4 * j4 + 1], hv.y, acc2[k]);
                acc2[k] = fmaf(whh2[4 * j4 + 2], hv.z, acc2[k]);
                acc2[k] = fmaf(whh2[4 * j4 + 3], hv.w, acc2[k]);
            }
        }
        g2_s[bp * 2 + 0][g2i] = acc2[0];
        g2_s[bp * 2 + 1][g2i] = acc2[1];
        __syncthreads();

        // ---- layer2 state update: threads t<128 -> unit t&31, batch t>>5 ----
        if (t < NB * H2) {
            const int u = t & (H2 - 1), b = t >> 5;
            const float gi = sigm(g2_s[b][u]);
            const float gf = sigm(g2_s[b][H2 + u]);
            const float gg = tanh_(g2_s[b][2 * H2 + u]);
            const float go = sigm(g2_s[b][3 * H2 + u]);
            c2 = fmaf(gf, c2, gi * gg);
            h2_s[b][u] = go * tanh_(c2);
        }
        __syncthreads();
    }

    // ================= FC head on final h2 =================
    float* fc_s = &g2_s[0][0];   // reuse as [NB][FCN]
    if (t < NB * FCN) {
        const int b = t / FCN, j = t % FCN;
        float s = fc1_b[j];
        #pragma unroll
        for (int k = 0; k < H2; ++k)
            s = fmaf(fc1_w[j * H2 + k], h2_s[b][k], s);
        fc_s[b * FCN + j] = fmaxf(s, 0.f);
    }
    __syncthreads();
    if (t < NB) {
        float s = fc2_b[0];
        #pragma unroll
        for (int j = 0; j < FCN; ++j)
            s = fmaf(fc2_w[j], fc_s[t * FCN + j], s);
        out[b0 + t] = s;
    }
}

extern "C" void kernel_launch(void* const* d_in, const int* in_sizes, int n_in,
                              void* d_out, int out_size, void* d_ws, size_t ws_size,
                              hipStream_t stream) {
    const float* x     = (const float*)d_in[0];
    const float* Wih1  = (const float*)d_in[1];
    const float* Whh1  = (const float*)d_in[2];
    const float* bih1  = (const float*)d_in[3];
    const float* bhh1  = (const float*)d_in[4];
    const float* Wih2  = (const float*)d_in[5];
    const float* Whh2  = (const float*)d_in[6];
    const float* bih2  = (const float*)d_in[7];
    const float* bhh2  = (const float*)d_in[8];
    const float* fc1_w = (const float*)d_in[9];
    const float* fc1_b = (const float*)d_in[10];
    const float* fc2_w = (const float*)d_in[11];
    const float* fc2_b = (const float*)d_in[12];
    float* out = (float*)d_out;

    const int n_batch = 2048;
    dim3 grid(n_batch / NB), block(BLK);
    lstm_fused<<<grid, block, 0, stream>>>(x, Wih1, Whh1, bih1, bhh1,
                                           Wih2, Whh2, bih2, bhh2,
                                           fc1_w, fc1_b, fc2_w, fc2_b, out);
}